// Round 18
// baseline (249.294 us; speedup 1.0000x reference)
//
#include <hip/hip_runtime.h>

#define N_NODES 50000
#define TOPK 32
#define SOFT_DELTA 2e-5f   // boundary-softening gap (GEMM err ~fp32 via 3-tier split)

typedef unsigned long long u64;
typedef unsigned u32;
typedef float f32x16 __attribute__((ext_vector_type(16)));
typedef __bf16 bf16x8 __attribute__((ext_vector_type(8)));

__device__ __forceinline__ float dec(u32 u) {   // inverse order-preserving map
    return __builtin_bit_cast(float, (u & 0x80000000u) ? (u & 0x7FFFFFFFu) : ~u);
}
__device__ __forceinline__ int mbcnt64(u64 m) { // popcount of mask at lanes < mine
    return __builtin_amdgcn_mbcnt_hi((u32)(m >> 32),
           __builtin_amdgcn_mbcnt_lo((u32)m, 0u));
}

// async global->LDS, 16B per lane; LDS dest = wave-uniform base + lane*16
__device__ __forceinline__ void gll16(const uint4* g, uint4* l) {
    __builtin_amdgcn_global_load_lds(
        (const __attribute__((address_space(1))) void*)g,
        (__attribute__((address_space(3))) void*)l, 16, 0, 0);
}

// 4-byte compact entry: (col << 16) | bf16bits(value).  col in [0,256).
__device__ __forceinline__ u32 enc4(float v, int col) {
    return ((u32)col << 16) |
           ((__builtin_bit_cast(u32, v) + 0x8000u) >> 16);
}

// round fp32 to bf16 (half-away), return packed pair + exact residuals
__device__ __forceinline__ u32 s2(float x0, float x1, float& r0, float& r1) {
    const u32 h0 = (__builtin_bit_cast(u32, x0) + 0x8000u) & 0xFFFF0000u;
    const u32 h1 = (__builtin_bit_cast(u32, x1) + 0x8000u) & 0xFFFF0000u;
    r0 = x0 - __builtin_bit_cast(float, h0);    // exact (mantissa tail fits fp32)
    r1 = x1 - __builtin_bit_cast(float, h1);
    return (h0 >> 16) | h1;
}
__device__ __forceinline__ u32 p2(float x0, float x1) {  // rounded pack, no residual
    return (((__builtin_bit_cast(u32, x0) + 0x8000u) & 0xFFFF0000u) >> 16) |
           ((__builtin_bit_cast(u32, x1) + 0x8000u) & 0xFFFF0000u);
}

struct Tri { uint4 h1, h2, h3; };
// 8 consecutive fp32 -> 3 bf16 tiers (x = h1 + h2 + h3 + O(2^-25 x))
__device__ __forceinline__ Tri cvt8(const float4 u, const float4 v, bool deep) {
    Tri t;
    float r0,r1,r2,r3,r4,r5,r6,r7;
    t.h1.x = s2(u.x, u.y, r0, r1);
    t.h1.y = s2(u.z, u.w, r2, r3);
    t.h1.z = s2(v.x, v.y, r4, r5);
    t.h1.w = s2(v.z, v.w, r6, r7);
    float s0,s1,s2_,s3,s4,s5,s6,s7;
    t.h2.x = s2(r0, r1, s0, s1);
    t.h2.y = s2(r2, r3, s2_, s3);
    t.h2.z = s2(r4, r5, s4, s5);
    t.h2.w = s2(r6, r7, s6, s7);
    if (deep) {
        t.h3.x = p2(s0, s1); t.h3.y = p2(s2_, s3);
        t.h3.z = p2(s4, s5); t.h3.w = p2(s6, s7);
    } else {
        t.h3 = make_uint4(0, 0, 0, 0);
    }
    return t;
}

// ---------------------------------------------------------------------------
// Kernel 0: W tier prepass (unchanged).
// WT[s*1024 + c*256 + j] uint4 = W[j][s*32 + c*8 .. +8] tiers.
// Wneigh: 3 tiers; Wself: tier-1 only.  8 blocks, ~3us, 512 KB ws.
// ---------------------------------------------------------------------------
__global__ __launch_bounds__(256) void wprep_kernel(
    const float* __restrict__ Wself, const float* __restrict__ Wneigh,
    uint4* __restrict__ WTn1, uint4* __restrict__ WTn2,
    uint4* __restrict__ WTn3, uint4* __restrict__ WTs1)
{
    for (int it = 0; it < 4; ++it) {
        const int id = (blockIdx.x * 4 + it) * 256 + threadIdx.x;  // 0..8191
        const int s = id >> 10, rem = id & 1023;
        const int c = rem >> 8, j = rem & 255;
        const float* srcN = Wneigh + (size_t)j * 256 + s * 32 + c * 8;
        const Tri tn = cvt8(*(const float4*)srcN, *(const float4*)(srcN + 4), true);
        WTn1[id] = tn.h1; WTn2[id] = tn.h2; WTn3[id] = tn.h3;
        const float* srcS = Wself + (size_t)j * 256 + s * 32 + c * 8;
        const Tri ts = cvt8(*(const float4*)srcS, *(const float4*)(srcS + 4), false);
        WTs1[id] = ts.h1;
    }
}

// ---------------------------------------------------------------------------
// Kernel 1 (R17 proven, ~106us): fully-fused GEMM (hself + fneigh) + top-32.
// 32x256 tiles, BK=16, 512 thr; 3 blocks/CU (occ 50%).  Unchanged.
// ---------------------------------------------------------------------------
__global__ __launch_bounds__(512, 3) void gemm_all_kernel(
    const float* __restrict__ feat,
    const uint4* __restrict__ WTn1, const uint4* __restrict__ WTn2,
    const uint4* __restrict__ WTn3, const uint4* __restrict__ WTs1,
    const float* __restrict__ bneigh,
    float* __restrict__ hself,          // d_out [N,256]
    u32*  __restrict__ compact,         // [N*32] (col<<16)|bf16bits(w*v)
    u64*  __restrict__ softList)        // [N]
{
    __shared__ uint4 SMEM[2304];        // 36 KB, region-aliased
    uint4* LBn1 = SMEM;                 // 512 each (B: 2ch x 256 cols)
    uint4* LBn2 = SMEM + 512;
    uint4* LBn3 = SMEM + 1024;
    uint4* LBs1 = SMEM + 1536;
    uint4* LA1  = SMEM + 2048;          // 64 each (A: 2ch x 32 rows)
    uint4* LA2  = SMEM + 2112;
    uint4* LA3  = SMEM + 2176;          // ..2240
    float* stage = (float*)SMEM;        // [32][256] fp32 after K-loop (32 KB)

    const int tid  = threadIdx.x;
    const int lane = tid & 63;
    const int wave = tid >> 6;          // 0..7 = output col group
    const int kg   = lane >> 5;         // k-chunk (8 elems) within BK=16

    const int row0 = blockIdx.x * 32;

    // A staging map (tid < 256): row = tid>>3, k-pair = tid&7 (float2 grain)
    const int ar  = tid >> 3;
    const int akp = tid & 7;
    int gra = row0 + ar;
    if (gra >= N_NODES) gra = row0;     // dummy (guarded on store / topk skip)
    const float* pa = feat + (size_t)gra * 256 + akp * 2;
    const int widx = ((akp >> 2) << 7) + (ar << 2) + (akp & 3);  // u32 index

    const int rA0  = lane & 31;
    const int bcol = wave * 32 + (lane & 31);   // this lane's output col

    f32x16 accN = (f32x16)0.f, accS = (f32x16)0.f;

    float2 va = make_float2(0.f, 0.f);
    if (tid < 256) va = *(const float2*)(pa);

    for (int s = 0; s < 16; ++s) {      // 16 K-steps of BK=16
        __syncthreads();                // previous step's LDS readers done
        {   // B: 4x async DMA (one 16B/lane per tier; 32 KB/block/step)
            const int bsrc = (s >> 1) * 1024 + (s & 1) * 512 + (wave << 6) + lane;
            const int bdst = wave << 6;
            gll16(WTn1 + bsrc, LBn1 + bdst);
            gll16(WTn2 + bsrc, LBn2 + bdst);
            gll16(WTn3 + bsrc, LBn3 + bdst);
            gll16(WTs1 + bsrc, LBs1 + bdst);
        }
        if (tid < 256) {                // A: 3-tier convert, float2 grain
            float r0, r1, q0, q1;
            const u32 h1 = s2(va.x, va.y, r0, r1);
            const u32 h2 = s2(r0, r1, q0, q1);
            const u32 h3 = p2(q0, q1);
            ((u32*)LA1)[widx] = h1;
            ((u32*)LA2)[widx] = h2;
            ((u32*)LA3)[widx] = h3;
            if (s < 15) va = *(const float2*)(pa + (s + 1) * 16);
        }
        __syncthreads();                // vmcnt+lgkm drain: tiles ready

        const int ia = (kg << 5) + rA0;         // uint4 idx into LA
        const int ib = (kg << 8) + bcol;        // uint4 idx into LB
        const bf16x8 a1 = __builtin_bit_cast(bf16x8, LA1[ia]);
        const bf16x8 a2 = __builtin_bit_cast(bf16x8, LA2[ia]);
        const bf16x8 a3 = __builtin_bit_cast(bf16x8, LA3[ia]);
        const bf16x8 b1 = __builtin_bit_cast(bf16x8, LBn1[ib]);
        const bf16x8 b2 = __builtin_bit_cast(bf16x8, LBn2[ib]);
        const bf16x8 b3 = __builtin_bit_cast(bf16x8, LBn3[ib]);
        const bf16x8 bs = __builtin_bit_cast(bf16x8, LBs1[ib]);

        accN = __builtin_amdgcn_mfma_f32_32x32x16_bf16(a1, b1, accN, 0, 0, 0);
        accN = __builtin_amdgcn_mfma_f32_32x32x16_bf16(a1, b2, accN, 0, 0, 0);
        accN = __builtin_amdgcn_mfma_f32_32x32x16_bf16(a2, b1, accN, 0, 0, 0);
        accN = __builtin_amdgcn_mfma_f32_32x32x16_bf16(a2, b2, accN, 0, 0, 0);
        accN = __builtin_amdgcn_mfma_f32_32x32x16_bf16(a1, b3, accN, 0, 0, 0);
        accN = __builtin_amdgcn_mfma_f32_32x32x16_bf16(a3, b1, accN, 0, 0, 0);
        accS = __builtin_amdgcn_mfma_f32_32x32x16_bf16(a1, bs, accS, 0, 0, 0);
        accS = __builtin_amdgcn_mfma_f32_32x32x16_bf16(a2, bs, accS, 0, 0, 0);
    }

    __syncthreads();                    // all MFMA LDS reads done: SMEM free
    // stage accN + bias -> stage[32][256]; store hself from accS (no LDS).
    const float bn = bneigh[bcol];
#pragma unroll
    for (int r = 0; r < 16; ++r) {
        const int rl = (kg << 2) + (r & 3) + ((r >> 2) << 3);  // row 0..31
        stage[rl * 256 + bcol] = accN[r] + bn;
        const int grow = row0 + rl;
        if (grow < N_NODES)
            hself[(size_t)grow * 256 + bcol] = accS[r];
    }
    __syncthreads();                    // cross-wave stage visible

    // per-wave top-32 on rows wave*4 .. +4 (R12 early-exit code, LDS-fed)
    for (int it = 0; it < 4; ++it) {
        const int rl  = wave * 4 + it;
        const int row = row0 + rl;
        if (row >= N_NODES) break;      // wave-uniform

        const float4 v4 = ((const float4*)stage)[rl * 64 + lane];
        const float vv[4] = {v4.x, v4.y, v4.z, v4.w};
        u32 key[4];
#pragma unroll
        for (int j = 0; j < 4; ++j) {
            const u32 b = __builtin_bit_cast(u32, vv[j]);
            key[j] = (b & 0x80000000u) ? ~b : (b | 0x80000000u);
        }

        u32 T = 0;
        bool resolved = false;
        for (int b = 31; b >= 0; --b) {
            const u32 t2 = T | (1u << b);
            int cnt = 0;
#pragma unroll
            for (int j = 0; j < 4; ++j) cnt += __popcll(__ballot(key[j] >= t2));
            if (cnt >= TOPK) T = t2;
            if (cnt == TOPK) { resolved = true; break; }
        }
        if (resolved) {
            u32 x = 0xFFFFFFFFu;
#pragma unroll
            for (int j = 0; j < 4; ++j)
                x = min(x, (key[j] >= T) ? key[j] : 0xFFFFFFFFu);
#pragma unroll
            for (int off = 32; off >= 1; off >>= 1)
                x = min(x, (u32)__shfl_xor((int)x, off, 64));
            T = x;                      // exact 32nd-largest key
        }

        u64 bgt[4], beq[4];
        int cgt = 0, ceq = 0;
#pragma unroll
        for (int j = 0; j < 4; ++j) {
            bgt[j] = __ballot(key[j] > T);
            beq[j] = __ballot(key[j] == T);
            cgt += __popcll(bgt[j]);
            ceq += __popcll(beq[j]);
        }
        const int r_ = TOPK - cgt;      // >= 1

        u32 m33;
        if (ceq > r_) {
            m33 = T;
        } else {
            u32 x = 0;
#pragma unroll
            for (int j = 0; j < 4; ++j) x = max(x, (key[j] < T) ? key[j] : 0u);
#pragma unroll
            for (int off = 32; off >= 1; off >>= 1)
                x = max(x, (u32)__shfl_xor((int)x, off, 64));
            m33 = x;
        }
        const float v32f = dec(T);
        const float v33f = dec(m33);
        const bool soft = (v32f - v33f) < SOFT_DELTA;

        const int meqsum = mbcnt64(beq[0]) + mbcnt64(beq[1]) +
                           mbcnt64(beq[2]) + mbcnt64(beq[3]);

        int gtbase = 0, selfpre = 0, spillcol = -1;
#pragma unroll
        for (int j = 0; j < 4; ++j) {
            const int col = lane * 4 + j;
            if (key[j] > T) {
                const int pos = gtbase + mbcnt64(bgt[j]);
                compact[(size_t)row * 32 + pos] = enc4(vv[j], col);
            } else if (key[j] == T) {
                const int eqrank = meqsum + selfpre;
                if (eqrank < r_) {
                    const float w = (soft && eqrank == r_ - 1) ? 0.5f : 1.0f;
                    compact[(size_t)row * 32 + (cgt + eqrank)] = enc4(vv[j] * w, col);
                } else if (eqrank == r_) {
                    spillcol = col;
                }
                ++selfpre;
            }
            gtbase += __popcll(bgt[j]);
        }

        if (soft) {
            const u64 valbits = (u64)__builtin_bit_cast(u32, 0.5f * v33f);
            if (ceq > r_) {
                if (spillcol >= 0)
                    softList[row] = (((u64)(u32)spillcol) << 32) | valbits;
            } else {
                int best = 1 << 30;
#pragma unroll
                for (int j = 0; j < 4; ++j) {
                    const u64 b33 = __ballot(key[j] == m33);
                    if (b33) best = min(best, ((int)__builtin_ctzll(b33)) * 4 + j);
                }
                if (lane == 0)
                    softList[row] = (((u64)(u32)best) << 32) | valbits;
            }
        } else if (lane == 0) {
            softList[row] = 0ull;
        }
    }
}

// ---------------------------------------------------------------------------
// Kernel 2 (R18): CSR SpMM, no LDS atomics, RMW-CHAIN SPLIT.  One wave per
// dst node; lanes 0-31 edge A, lanes 32-63 edge B (distinct cols per edge).
// R18: each half gets TWO sub-accumulators indexed by edge parity (k&1,
// compile-time in the unrolled loop) -> the 8 sequential LDS RMWs per
// 16-edge step (cols may collide ACROSS edges, compiler must order them)
// split into two interleaved 4-deep chains.  LDS 16->32 KB (still 4
// blocks/CU at the 2048-thread cap); epilogue merges 4 arrays.
// ---------------------------------------------------------------------------
__global__ __launch_bounds__(512) void spmm_kernel(
    const u32* __restrict__ compact,   // [N*32] 4B entries
    const u64* __restrict__ softList,  // [N]
    const int* __restrict__ indices,   // [E]
    const int* __restrict__ indptr,    // [N+1]
    float* __restrict__ inout)         // d_out: in = h_self, out = result
{
    __shared__ float accs[8][2][2][256];  // 32 KB: wave, half, sub(k&1)

    const int lane = threadIdx.x & 63;
    const int wave = threadIdx.x >> 6;
    const int node = blockIdx.x * 8 + wave;   // grid*8 == N exactly
    const int half = lane >> 5;
    const int e    = lane & 31;
    float* acc0 = accs[wave][half][0];
    float* acc1 = accs[wave][half][1];

    // zero wave's 4 KB slice: 256 float4s / 64 lanes = 4 each
    {
        const float4 z4 = make_float4(0.f, 0.f, 0.f, 0.f);
        float4* wslice = (float4*)&accs[wave][0][0][0];
#pragma unroll
        for (int q = 0; q < 4; ++q) wslice[q * 64 + lane] = z4;
    }

    const int start = indptr[node];
    const int deg   = indptr[node + 1] - start;
    const float4 hs = ((const float4*)(inout + (size_t)node * 256))[lane];

    for (int base = 0; base < deg; base += 64) {
        const int n = min(64, deg - base);
        const int myidx = (base + lane < deg) ? indices[start + base + lane] : 0;
        for (int d = 0; d < n; d += 16) {          // 8 pairs = 16 edges
            int s[8]; bool ok[8]; u32 ent[8];
#pragma unroll
            for (int k = 0; k < 8; ++k) {
                const int ei = d + 2 * k + half;
                ok[k] = ei < n;
                s[k]  = __shfl(myidx, min(ei, n - 1), 64);
                ent[k] = compact[(size_t)s[k] * 32 + e];   // coalesced 128B/edge
            }
            u64 se[8];
            if (e == 0) {
#pragma unroll
                for (int k = 0; k < 8; ++k) se[k] = softList[s[k]];
            }
#pragma unroll
            for (int k = 0; k < 8; ++k) {
                const int c = (int)(ent[k] >> 16);
                float v = __builtin_bit_cast(float, ent[k] << 16);
                if (!ok[k]) v = 0.f;               // clamped tail: add 0
                float* a = (k & 1) ? acc1 : acc0;  // static in unrolled loop
                a[c] += v;                         // 2 interleaved 4-deep chains
                if (e == 0 && ok[k]) {
                    const u32 vb = (u32)se[k];
                    if (vb)
                        acc0[(int)(se[k] >> 32)] += __builtin_bit_cast(float, vb);
                }
            }
        }
    }

    // merge 4 sub-accumulators + h_self (wave-private, lgkmcnt-ordered)
    const float4 a00 = ((const float4*)&accs[wave][0][0][0])[lane];
    const float4 a01 = ((const float4*)&accs[wave][0][1][0])[lane];
    const float4 a10 = ((const float4*)&accs[wave][1][0][0])[lane];
    const float4 a11 = ((const float4*)&accs[wave][1][1][0])[lane];
    float4 o;
    o.x = (a00.x + a01.x) + (a10.x + a11.x) + hs.x;
    o.y = (a00.y + a01.y) + (a10.y + a11.y) + hs.y;
    o.z = (a00.z + a01.z) + (a10.z + a11.z) + hs.z;
    o.w = (a00.w + a01.w) + (a10.w + a11.w) + hs.w;
    ((float4*)(inout + (size_t)node * 256))[lane] = o;
}

// ---------------------------------------------------------------------------
extern "C" void kernel_launch(void* const* d_in, const int* in_sizes, int n_in,
                              void* d_out, int out_size, void* d_ws, size_t ws_size,
                              hipStream_t stream) {
    const float* feat   = (const float*)d_in[0];
    const float* Wself  = (const float*)d_in[1];
    const float* Wneigh = (const float*)d_in[2];
    const float* bneigh = (const float*)d_in[3];
    const int* indices  = (const int*)d_in[4];
    const int* indptr   = (const int*)d_in[5];
    float* out = (float*)d_out;

    char* ws       = (char*)d_ws;
    u32*  compact  = (u32*)(ws);                       // 6.4 MB
    u64*  softList = (u64*)(ws + 6400000);             // 0.4 MB
    uint4* WTn1    = (uint4*)(ws + 6800000);           // 4 x 128 KB
    uint4* WTn2    = WTn1 + 8192;
    uint4* WTn3    = WTn2 + 8192;
    uint4* WTs1    = WTn3 + 8192;

    wprep_kernel<<<dim3(8), dim3(256), 0, stream>>>(
        Wself, Wneigh, WTn1, WTn2, WTn3, WTs1);

    const int rowTiles32 = (N_NODES + 31) / 32;        // 1563
    gemm_all_kernel<<<dim3(rowTiles32), dim3(512), 0, stream>>>(
        feat, WTn1, WTn2, WTn3, WTs1, bneigh, out, compact, softList);

    const int spmmBlocks = N_NODES / 8;                // 6250 (exact)
    spmm_kernel<<<dim3(spmmBlocks), dim3(512), 0, stream>>>(
        compact, softList, indices, indptr, out);
}